// Round 2
// baseline (2018.536 us; speedup 1.0000x reference)
//
#include <hip/hip_runtime.h>
#include <hip/hip_bf16.h>

// ---------------------------------------------------------------------------
// HybridCnnLnn R17: R16 structure (butterfly reduce, 1 barrier/unfold) with
// the spill fixed:
//  - __launch_bounds__(1024, 4): allocator budget 128 VGPR (R16's counters
//    showed a 64-VGPR cap + 164MB scratch writes -> spill explosion).
//  - r12 table back to LDS (128KB, [n*1024+tid], stride-1 float2 = free
//    2-way aliasing) -> -32 VGPR.
//  - sensory tables de-padded into regs: (scale,bias) float2 + weight float
//    = 48 regs (vs 64 for float4-with-pad). No global streams left in the
//    t-loop, nothing for LICM to hoist-spill.
//  - feats double-buffered in LDS: prefetch t+1 at loop top, LDS-write
//    parked at unfold u=4 -> 6 barriers/t, HBM latency hidden.
// Arithmetic op-for-op identical to R16 -> absmax 0.0 expected.
// ---------------------------------------------------------------------------

#define L2E 1.4426950408889634f

// ---------------- prep: fold params, transpose to [n][j*8+h] ---------------
__global__ __launch_bounds__(256)
void prep_kernel(const float* __restrict__ smu, const float* __restrict__ ssig,
                 const float* __restrict__ sW,  const float* __restrict__ serev,
                 const float* __restrict__ mu,  const float* __restrict__ sig,
                 const float* __restrict__ W,   const float* __restrict__ erev,
                 const float* __restrict__ in_w, const float* __restrict__ in_b,
                 float2* __restrict__ R12T, float* __restrict__ VTT,
                 float2* __restrict__ S2T, float* __restrict__ SWT) {
  int idx = blockIdx.x * 256 + threadIdx.x;      // idx = i*128 + j
  int i = idx >> 7, j = idx & 127;
  int h = i >> 4, n = i & 15;
  int dst = n * 1024 + j * 8 + h;                // lane-major for lnn mapping
  float r1 = sig[idx] * L2E;
  R12T[dst] = make_float2(r1, mu[idx] * r1);     // arg = r2 - r1*v
  VTT[dst]  = W[idx] * erev[idx];                // |erev|=1 -> |VT| = W
  float ss = ssig[idx] * L2E;
  S2T[dst] = make_float2(ss * in_w[i], (smu[idx] - in_b[i]) * ss);
  SWT[dst] = sW[idx] * serev[idx];
}

// ----------------------------- conv1 (k=5, tiled) --------------------------
// x [512,256,24] -> P1 [512,64,128] ([b][co][t']), relu+maxpool2 fused
__launch_bounds__(512)
__global__ void conv1_kernel(const float* __restrict__ x, const float* __restrict__ w1,
                             const float* __restrict__ b1, float* __restrict__ P1) {
  __shared__ float xs[6240];                     // rows t in [-2,258), 24 ch
  int tid = threadIdx.x, b = blockIdx.x;
  const float* xb = x + (size_t)b * 6144;
  for (int idx = tid; idx < 6144; idx += 512) xs[idx + 48] = xb[idx];
  if (tid < 48) { xs[tid] = 0.f; xs[6192 + tid] = 0.f; }
  __syncthreads();
  int tp = tid & 127, cq = tid >> 7;             // 128 pooled t x 4 co-quarters
  float acc0[16], acc1[16];
#pragma unroll
  for (int n = 0; n < 16; n++) { float bb = b1[cq * 16 + n]; acc0[n] = bb; acc1[n] = bb; }
  for (int cic = 0; cic < 3; cic++) {            // ci chunks of 8
    float p[6][8];
#pragma unroll
    for (int r = 0; r < 6; r++) {
      const float* row = &xs[(2 * tp + r) * 24 + cic * 8];
      float4 a = *(const float4*)row;
      float4 c = *(const float4*)(row + 4);
      p[r][0] = a.x; p[r][1] = a.y; p[r][2] = a.z; p[r][3] = a.w;
      p[r][4] = c.x; p[r][5] = c.y; p[r][6] = c.z; p[r][7] = c.w;
    }
#pragma unroll
    for (int n = 0; n < 16; n++) {
      const float* wr = w1 + (cq * 16 + n) * 120 + cic * 40;  // uniform -> s_load
#pragma unroll
      for (int c = 0; c < 8; c++) {
#pragma unroll
        for (int kk = 0; kk < 5; kk++) {
          float w = wr[c * 5 + kk];
          acc0[n] = fmaf(p[kk][c],     w, acc0[n]);
          acc1[n] = fmaf(p[kk + 1][c], w, acc1[n]);
        }
      }
    }
  }
  float* pb = P1 + (size_t)b * 8192;
#pragma unroll
  for (int n = 0; n < 16; n++)
    pb[(cq * 16 + n) * 128 + tp] = fmaxf(fmaxf(acc0[n], acc1[n]), 0.f);
}

// ----------------------------- conv2 (k=3, tiled) --------------------------
// P1 [512,64,128] -> feats [512,64,128] laid out [b][t'][co]
__launch_bounds__(512)
__global__ void conv2_kernel(const float* __restrict__ P1, const float* __restrict__ w2,
                             const float* __restrict__ b2, float* __restrict__ feats) {
  __shared__ float xs[8450];                     // [t+1][ci], stride 65
  int tid = threadIdx.x, b = blockIdx.x;
  const float* pb = P1 + (size_t)b * 8192;
  for (int idx = tid; idx < 8192; idx += 512) {
    int ci = idx >> 7, t = idx & 127;
    xs[(t + 1) * 65 + ci] = pb[idx];
  }
  if (tid < 65) { xs[tid] = 0.f; xs[129 * 65 + tid] = 0.f; }
  __syncthreads();
  int tp = tid & 63, cq = tid >> 6;              // 64 pooled t x 8 co-octants
  float acc0[16], acc1[16];
#pragma unroll
  for (int n = 0; n < 16; n++) { float bb = b2[cq * 16 + n]; acc0[n] = bb; acc1[n] = bb; }
  for (int cic = 0; cic < 8; cic++) {            // ci chunks of 8
    float p[4][8];
#pragma unroll
    for (int r = 0; r < 4; r++)
#pragma unroll
      for (int c = 0; c < 8; c++)
        p[r][c] = xs[(2 * tp + r) * 65 + cic * 8 + c];
#pragma unroll
    for (int n = 0; n < 16; n++) {
      const float* wr = w2 + (cq * 16 + n) * 192 + cic * 24;  // native [co][ci][kk]
#pragma unroll
      for (int c = 0; c < 8; c++) {
#pragma unroll
        for (int kk = 0; kk < 3; kk++) {
          float w = wr[c * 3 + kk];
          acc0[n] = fmaf(p[kk][c],     w, acc0[n]);
          acc1[n] = fmaf(p[kk + 1][c], w, acc1[n]);
        }
      }
    }
  }
  __syncthreads();                               // reuse xs as [tp][co]
#pragma unroll
  for (int n = 0; n < 16; n += 4) {
    float4 v;
    v.x = fmaxf(fmaxf(acc0[n],     acc1[n]),     0.f);
    v.y = fmaxf(fmaxf(acc0[n + 1], acc1[n + 1]), 0.f);
    v.z = fmaxf(fmaxf(acc0[n + 2], acc1[n + 2]), 0.f);
    v.w = fmaxf(fmaxf(acc0[n + 3], acc1[n + 3]), 0.f);
    *(float4*)&xs[tp * 128 + cq * 16 + n] = v;
  }
  __syncthreads();
  float* fb = feats + (size_t)b * 8192;
  for (int idx = tid; idx < 8192; idx += 512) fb[idx] = xs[idx];
}

// --------------------------- LTC recurrence + head -------------------------
// block = 1024: h = tid&7 (i-octant), j = tid>>3 (unit). 2 batches/block,
// grid 256 = 1 block/CU. r12 in LDS (128KB); sensory tables + vw in 64 VGPR;
// per-unfold: 16 reg/LDS iters -> 3x shfl_xor butterfly -> leader update ->
// ping-pong vbuf write -> ONE barrier. feats double-buffered (write at u=4).
__launch_bounds__(1024, 4)
__global__ void lnn_kernel(const float2* __restrict__ R12T, const float* __restrict__ VTT,
                           const float2* __restrict__ S2T, const float* __restrict__ SWT,
                           const float* __restrict__ feats,
                           const float* __restrict__ cm_t, const float* __restrict__ gleak,
                           const float* __restrict__ vleak,
                           const float* __restrict__ fc1_w, const float* __restrict__ fc1_b,
                           const float* __restrict__ fc2_w, const float* __restrict__ fc2_b,
                           float* __restrict__ out) {
  __shared__ float2 r12lds[16384];               // 128KB: [n*1024 + tid]
  __shared__ float2 xt2[2][136];                 // feats double-buffer, padded
  __shared__ float2 vbuf[2][136];                // ping-pong v, padded slots
  __shared__ float red[2][64];
  int tid = threadIdx.x;
  int h = tid & 7, j = tid >> 3;
  int b0 = blockIdx.x * 2;

  // stage r12 table (16 coalesced float2 iters)
  for (int idx = tid; idx < 16384; idx += 1024) r12lds[idx] = R12T[idx];

  // sensory tables + vw -> registers (coalesced [n][tid] layout from prep)
  float2 s2[16]; float sw[16], vw[16];
#pragma unroll
  for (int n = 0; n < 16; n++) {
    s2[n] = S2T[n * 1024 + tid];
    sw[n] = SWT[n * 1024 + tid];
    vw[n] = VTT[n * 1024 + tid];
  }

  float cmj = cm_t[j], glk = gleak[j];
  float gvl = glk * vleak[j], cgl = cmj + glk;
  float vj0 = 0.f, vj1 = 0.f;
  if (tid < 136) vbuf[0][tid] = make_float2(0.f, 0.f);
  const float* f0 = feats + (size_t)b0 * 8192;
  const float* f1 = f0 + 8192;
  if (tid < 128) xt2[0][tid + (tid >> 4)] = make_float2(f0[tid], f1[tid]);
  __syncthreads();

  const int hb = 17 * h;                         // slot base: 16h + n + h
  const float2* rp = r12lds + tid;

  for (int t = 0; t < 64; t++) {
    // prefetch feats for t+1; LDS-write parked at unfold u=4
    float pf0 = 0.f, pf1 = 0.f;
    if (tid < 128 && t < 63) {
      pf0 = f0[(t + 1) * 128 + tid];
      pf1 = f1[(t + 1) * 128 + tid];
    }

    // ---- sensory partials (all tables in regs, xt from LDS broadcast) ----
    float sn0 = 0.f, sd0 = 0.f, sn1 = 0.f, sd1 = 0.f;
    {
      const float2* xb = xt2[t & 1];
#pragma unroll
      for (int n = 0; n < 16; n++) {
        float2 xv = xb[hb + n];
        float2 s = s2[n];
        float q0 = __builtin_amdgcn_rcpf(1.f + __builtin_amdgcn_exp2f(fmaf(-s.x, xv.x, s.y)));
        sn0 = fmaf(sw[n], q0, sn0); sd0 = fmaf(fabsf(sw[n]), q0, sd0);
        float q1 = __builtin_amdgcn_rcpf(1.f + __builtin_amdgcn_exp2f(fmaf(-s.x, xv.y, s.y)));
        sn1 = fmaf(sw[n], q1, sn1); sd1 = fmaf(fabsf(sw[n]), q1, sd1);
      }
    }

    // ---- 6 semi-implicit ODE unfolds ----
#pragma unroll
    for (int u = 0; u < 6; u++) {
      float n0 = sn0, d0 = sd0, n1 = sn1, d1 = sd1;
      const float2* vb = vbuf[u & 1] + hb;
#pragma unroll
      for (int n = 0; n < 16; n++) {
        float2 rr = rp[n * 1024];                // stride-1 b64, free 2-way
        float2 v2 = vb[n];                       // 8-way broadcast, conflict-free
        float q0 = __builtin_amdgcn_rcpf(1.f + __builtin_amdgcn_exp2f(fmaf(-rr.x, v2.x, rr.y)));
        n0 = fmaf(vw[n], q0, n0); d0 = fmaf(fabsf(vw[n]), q0, d0);
        float q1 = __builtin_amdgcn_rcpf(1.f + __builtin_amdgcn_exp2f(fmaf(-rr.x, v2.y, rr.y)));
        n1 = fmaf(vw[n], q1, n1); d1 = fmaf(fabsf(vw[n]), q1, d1);
      }
      // butterfly reduce over the 8 octant lanes (adjacent lanes)
#pragma unroll
      for (int m = 1; m < 8; m <<= 1) {
        n0 += __shfl_xor(n0, m, 64);
        d0 += __shfl_xor(d0, m, 64);
        n1 += __shfl_xor(n1, m, 64);
        d1 += __shfl_xor(d1, m, 64);
      }
      if (u == 4 && tid < 128 && t < 63)         // park prefetched feats
        xt2[(t + 1) & 1][tid + (tid >> 4)] = make_float2(pf0, pf1);
      if (h == 0) {                              // leader lane per unit
        float den0 = cgl + d0, den1 = cgl + d1;
        float i0 = __builtin_amdgcn_rcpf(den0); i0 = i0 * fmaf(-den0, i0, 2.f);
        float i1 = __builtin_amdgcn_rcpf(den1); i1 = i1 * fmaf(-den1, i1, 2.f);
        vj0 = (fmaf(cmj, vj0, gvl) + n0) * i0;
        vj1 = (fmaf(cmj, vj1, gvl) + n1) * i1;
        vbuf[(u + 1) & 1][j + (j >> 4)] = make_float2(vj0, vj1);
      }
      __syncthreads();                           // the ONLY barrier per unfold
    }
  }

  // ---- MLP head (final v sits in vbuf[0] after 6 flips) ----
  if (tid < 128) {
    int g = tid >> 6, d = tid & 63;
    float acc = fc1_b[d];
    for (int u = 0; u < 128; u++) {
      float2 v2 = vbuf[0][u + (u >> 4)];
      acc = fmaf(g ? v2.y : v2.x, fc1_w[d * 128 + u], acc);
    }
    red[g][d] = fmaxf(acc, 0.f) * fc2_w[d];
  }
  __syncthreads();
  if (tid < 2) {
    float s = fc2_b[0];
    for (int d = 0; d < 64; d++) s += red[tid][d];
    out[b0 + tid] = s;
  }
}

// ------------------------------- launcher ----------------------------------
extern "C" void kernel_launch(void* const* d_in, const int* in_sizes, int n_in,
                              void* d_out, int out_size, void* d_ws, size_t ws_size,
                              hipStream_t stream) {
  (void)in_sizes; (void)n_in; (void)out_size; (void)ws_size;
  char* ws = (char*)d_ws;
  // 32MB envelope, time-multiplexed:
  //   P1 [0,16M) live conv1->conv2; tables [0,384K) after conv2 (prep);
  //   feats [16M,32M) live conv2->lnn.
  float*  P1   = (float*)(ws);
  float*  feats= (float*)(ws + (16 << 20));
  float2* R12T = (float2*)(ws + 0);             // 128KB
  float*  VTT  = (float*)(ws + (128 << 10));    // 64KB
  float2* S2T  = (float2*)(ws + (192 << 10));   // 128KB
  float*  SWT  = (float*)(ws + (320 << 10));    // 64KB -> ends 384KB

  conv1_kernel<<<512, 512, 0, stream>>>((const float*)d_in[0],
      (const float*)d_in[1], (const float*)d_in[2], P1);
  conv2_kernel<<<512, 512, 0, stream>>>(P1,
      (const float*)d_in[3], (const float*)d_in[4], feats);
  prep_kernel<<<64, 256, 0, stream>>>(
      (const float*)d_in[7], (const float*)d_in[8],
      (const float*)d_in[9], (const float*)d_in[10],
      (const float*)d_in[11], (const float*)d_in[12],
      (const float*)d_in[13], (const float*)d_in[14],
      (const float*)d_in[5], (const float*)d_in[6],
      R12T, VTT, S2T, SWT);
  lnn_kernel<<<256, 1024, 0, stream>>>(R12T, VTT, S2T, SWT, feats,
      (const float*)d_in[17], (const float*)d_in[16], (const float*)d_in[15],
      (const float*)d_in[18], (const float*)d_in[19],
      (const float*)d_in[20], (const float*)d_in[21],
      (float*)d_out);
}

// Round 3
// 1309.815 us; speedup vs baseline: 1.5411x; 1.5411x over previous
//
#include <hip/hip_runtime.h>
#include <hip/hip_bf16.h>

// ---------------------------------------------------------------------------
// HybridCnnLnn R18: R16/R17 structure with R15 register economics.
// Ledger: R15 (S4 streamed, 56 VGPR) = no spill, 1085us. R16/R17 (tables in
// regs) = spill explosion (VGPR capped at 64 for 1024-thr blocks; 107-164MB
// scratch writes, up to 3.2GB HBM reloads). => design for <=64 VGPRs:
//  - sensory table: packed float4 STREAMED from L2 inside the t-loop
//    (R15-proven shape: unroll 8, loads stay in-loop, table is L2-resident).
//  - r12 in LDS (reused 6x/t); vw in 16 regs (R15-proven).
//  - KEEP: butterfly shfl_xor reduce (no psum round-trip, no serial section),
//    1 barrier/unfold (6/t vs R15's ~15/t), feats double-buffer w/ prefetch.
// Arithmetic op-for-op identical to R15 -> absmax 0.0 expected.
// ---------------------------------------------------------------------------

#define L2E 1.4426950408889634f

// ---------------- prep: fold params, transpose to [n][j*8+h] ---------------
__global__ __launch_bounds__(256)
void prep_kernel(const float* __restrict__ smu, const float* __restrict__ ssig,
                 const float* __restrict__ sW,  const float* __restrict__ serev,
                 const float* __restrict__ mu,  const float* __restrict__ sig,
                 const float* __restrict__ W,   const float* __restrict__ erev,
                 const float* __restrict__ in_w, const float* __restrict__ in_b,
                 float2* __restrict__ R12T, float* __restrict__ VTT,
                 float4* __restrict__ S4T) {
  int idx = blockIdx.x * 256 + threadIdx.x;      // idx = i*128 + j
  int i = idx >> 7, j = idx & 127;
  int h = i >> 4, n = i & 15;
  int dst = n * 1024 + j * 8 + h;                // lane-major for lnn mapping
  float r1 = sig[idx] * L2E;
  R12T[dst] = make_float2(r1, mu[idx] * r1);     // arg = r2 - r1*v
  VTT[dst]  = W[idx] * erev[idx];                // |erev|=1 -> |VT| = W
  float ss = ssig[idx] * L2E;
  S4T[dst] = make_float4(ss * in_w[i], (smu[idx] - in_b[i]) * ss,
                         sW[idx] * serev[idx], 0.f);
}

// ----------------------------- conv1 (k=5, tiled) --------------------------
// x [512,256,24] -> P1 [512,64,128] ([b][co][t']), relu+maxpool2 fused
__launch_bounds__(512)
__global__ void conv1_kernel(const float* __restrict__ x, const float* __restrict__ w1,
                             const float* __restrict__ b1, float* __restrict__ P1) {
  __shared__ float xs[6240];                     // rows t in [-2,258), 24 ch
  int tid = threadIdx.x, b = blockIdx.x;
  const float* xb = x + (size_t)b * 6144;
  for (int idx = tid; idx < 6144; idx += 512) xs[idx + 48] = xb[idx];
  if (tid < 48) { xs[tid] = 0.f; xs[6192 + tid] = 0.f; }
  __syncthreads();
  int tp = tid & 127, cq = tid >> 7;             // 128 pooled t x 4 co-quarters
  float acc0[16], acc1[16];
#pragma unroll
  for (int n = 0; n < 16; n++) { float bb = b1[cq * 16 + n]; acc0[n] = bb; acc1[n] = bb; }
  for (int cic = 0; cic < 3; cic++) {            // ci chunks of 8
    float p[6][8];
#pragma unroll
    for (int r = 0; r < 6; r++) {
      const float* row = &xs[(2 * tp + r) * 24 + cic * 8];
      float4 a = *(const float4*)row;
      float4 c = *(const float4*)(row + 4);
      p[r][0] = a.x; p[r][1] = a.y; p[r][2] = a.z; p[r][3] = a.w;
      p[r][4] = c.x; p[r][5] = c.y; p[r][6] = c.z; p[r][7] = c.w;
    }
#pragma unroll
    for (int n = 0; n < 16; n++) {
      const float* wr = w1 + (cq * 16 + n) * 120 + cic * 40;  // uniform -> s_load
#pragma unroll
      for (int c = 0; c < 8; c++) {
#pragma unroll
        for (int kk = 0; kk < 5; kk++) {
          float w = wr[c * 5 + kk];
          acc0[n] = fmaf(p[kk][c],     w, acc0[n]);
          acc1[n] = fmaf(p[kk + 1][c], w, acc1[n]);
        }
      }
    }
  }
  float* pb = P1 + (size_t)b * 8192;
#pragma unroll
  for (int n = 0; n < 16; n++)
    pb[(cq * 16 + n) * 128 + tp] = fmaxf(fmaxf(acc0[n], acc1[n]), 0.f);
}

// ----------------------------- conv2 (k=3, tiled) --------------------------
// P1 [512,64,128] -> feats [512,64,128] laid out [b][t'][co]
__launch_bounds__(512)
__global__ void conv2_kernel(const float* __restrict__ P1, const float* __restrict__ w2,
                             const float* __restrict__ b2, float* __restrict__ feats) {
  __shared__ float xs[8450];                     // [t+1][ci], stride 65
  int tid = threadIdx.x, b = blockIdx.x;
  const float* pb = P1 + (size_t)b * 8192;
  for (int idx = tid; idx < 8192; idx += 512) {
    int ci = idx >> 7, t = idx & 127;
    xs[(t + 1) * 65 + ci] = pb[idx];
  }
  if (tid < 65) { xs[tid] = 0.f; xs[129 * 65 + tid] = 0.f; }
  __syncthreads();
  int tp = tid & 63, cq = tid >> 6;              // 64 pooled t x 8 co-octants
  float acc0[16], acc1[16];
#pragma unroll
  for (int n = 0; n < 16; n++) { float bb = b2[cq * 16 + n]; acc0[n] = bb; acc1[n] = bb; }
  for (int cic = 0; cic < 8; cic++) {            // ci chunks of 8
    float p[4][8];
#pragma unroll
    for (int r = 0; r < 4; r++)
#pragma unroll
      for (int c = 0; c < 8; c++)
        p[r][c] = xs[(2 * tp + r) * 65 + cic * 8 + c];
#pragma unroll
    for (int n = 0; n < 16; n++) {
      const float* wr = w2 + (cq * 16 + n) * 192 + cic * 24;  // native [co][ci][kk]
#pragma unroll
      for (int c = 0; c < 8; c++) {
#pragma unroll
        for (int kk = 0; kk < 3; kk++) {
          float w = wr[c * 3 + kk];
          acc0[n] = fmaf(p[kk][c],     w, acc0[n]);
          acc1[n] = fmaf(p[kk + 1][c], w, acc1[n]);
        }
      }
    }
  }
  __syncthreads();                               // reuse xs as [tp][co]
#pragma unroll
  for (int n = 0; n < 16; n += 4) {
    float4 v;
    v.x = fmaxf(fmaxf(acc0[n],     acc1[n]),     0.f);
    v.y = fmaxf(fmaxf(acc0[n + 1], acc1[n + 1]), 0.f);
    v.z = fmaxf(fmaxf(acc0[n + 2], acc1[n + 2]), 0.f);
    v.w = fmaxf(fmaxf(acc0[n + 3], acc1[n + 3]), 0.f);
    *(float4*)&xs[tp * 128 + cq * 16 + n] = v;
  }
  __syncthreads();
  float* fb = feats + (size_t)b * 8192;
  for (int idx = tid; idx < 8192; idx += 512) fb[idx] = xs[idx];
}

// --------------------------- LTC recurrence + head -------------------------
// block = 1024: h = tid&7 (i-octant), j = tid>>3 (unit). 2 batches/block,
// grid 256 = 1 block/CU. r12 in LDS (128KB); vw in 16 regs; sensory S4
// STREAMED from L2 inside the t-loop (R15 register economics, <=64 VGPR).
// Per-unfold: 16 LDS iters -> 3x shfl_xor butterfly -> leader update ->
// ping-pong vbuf write -> ONE barrier. feats double-buffered (write at u=4).
__launch_bounds__(1024)
__global__ void lnn_kernel(const float2* __restrict__ R12T, const float* __restrict__ VTT,
                           const float4* __restrict__ S4T,
                           const float* __restrict__ feats,
                           const float* __restrict__ cm_t, const float* __restrict__ gleak,
                           const float* __restrict__ vleak,
                           const float* __restrict__ fc1_w, const float* __restrict__ fc1_b,
                           const float* __restrict__ fc2_w, const float* __restrict__ fc2_b,
                           float* __restrict__ out) {
  __shared__ float2 r12lds[16384];               // 128KB: [n*1024 + tid]
  __shared__ float2 xt2[2][136];                 // feats double-buffer, padded
  __shared__ float2 vbuf[2][136];                // ping-pong v, padded slots
  __shared__ float red[2][64];
  int tid = threadIdx.x;
  int h = tid & 7, j = tid >> 3;
  int b0 = blockIdx.x * 2;

  // stage r12 table (16 coalesced float2 iters)
  for (int idx = tid; idx < 16384; idx += 1024) r12lds[idx] = R12T[idx];

  // vw -> 16 regs (coalesced [n][tid] layout from prep)
  float vw[16];
#pragma unroll
  for (int n = 0; n < 16; n++) vw[n] = VTT[n * 1024 + tid];

  float cmj = cm_t[j], glk = gleak[j];
  float gvl = glk * vleak[j], cgl = cmj + glk;
  float vj0 = 0.f, vj1 = 0.f;
  if (tid < 136) vbuf[0][tid] = make_float2(0.f, 0.f);
  const float* f0 = feats + (size_t)b0 * 8192;
  const float* f1 = f0 + 8192;
  if (tid < 128) xt2[0][tid + (tid >> 4)] = make_float2(f0[tid], f1[tid]);
  __syncthreads();

  const int hb = 17 * h;                         // slot base: 16h + n + h
  const float2* rp = r12lds + tid;
  const float4* sp = S4T + tid;

  for (int t = 0; t < 64; t++) {
    // prefetch feats for t+1; LDS-write parked at unfold u=4
    float pf0 = 0.f, pf1 = 0.f;
    if (tid < 128 && t < 63) {
      pf0 = f0[(t + 1) * 128 + tid];
      pf1 = f1[(t + 1) * 128 + tid];
    }

    // ---- sensory partials (S4 streamed from L2 in-loop; R15 shape) ----
    float sn0 = 0.f, sd0 = 0.f, sn1 = 0.f, sd1 = 0.f;
    {
      const float2* xb = xt2[t & 1];
#pragma unroll 8
      for (int n = 0; n < 16; n++) {
        float4 s = sp[n * 1024];
        float2 xv = xb[hb + n];
        float q0 = __builtin_amdgcn_rcpf(1.f + __builtin_amdgcn_exp2f(fmaf(-s.x, xv.x, s.y)));
        sn0 = fmaf(s.z, q0, sn0); sd0 = fmaf(fabsf(s.z), q0, sd0);
        float q1 = __builtin_amdgcn_rcpf(1.f + __builtin_amdgcn_exp2f(fmaf(-s.x, xv.y, s.y)));
        sn1 = fmaf(s.z, q1, sn1); sd1 = fmaf(fabsf(s.z), q1, sd1);
      }
    }

    // ---- 6 semi-implicit ODE unfolds (LDS-only inner loop) ----
    for (int u = 0; u < 6; u++) {
      float n0 = sn0, d0 = sd0, n1 = sn1, d1 = sd1;
      const float2* vb = vbuf[u & 1] + hb;
#pragma unroll
      for (int n = 0; n < 16; n++) {
        float2 rr = rp[n * 1024];                // stride-1 b64, free 2-way
        float2 v2 = vb[n];                       // 8-way broadcast, conflict-free
        float q0 = __builtin_amdgcn_rcpf(1.f + __builtin_amdgcn_exp2f(fmaf(-rr.x, v2.x, rr.y)));
        n0 = fmaf(vw[n], q0, n0); d0 = fmaf(fabsf(vw[n]), q0, d0);
        float q1 = __builtin_amdgcn_rcpf(1.f + __builtin_amdgcn_exp2f(fmaf(-rr.x, v2.y, rr.y)));
        n1 = fmaf(vw[n], q1, n1); d1 = fmaf(fabsf(vw[n]), q1, d1);
      }
      // butterfly reduce over the 8 octant lanes (adjacent lanes)
#pragma unroll
      for (int m = 1; m < 8; m <<= 1) {
        n0 += __shfl_xor(n0, m, 64);
        d0 += __shfl_xor(d0, m, 64);
        n1 += __shfl_xor(n1, m, 64);
        d1 += __shfl_xor(d1, m, 64);
      }
      if (u == 4 && tid < 128 && t < 63)         // park prefetched feats
        xt2[(t + 1) & 1][tid + (tid >> 4)] = make_float2(pf0, pf1);
      if (h == 0) {                              // leader lane per unit
        float den0 = cgl + d0, den1 = cgl + d1;
        float i0 = __builtin_amdgcn_rcpf(den0); i0 = i0 * fmaf(-den0, i0, 2.f);
        float i1 = __builtin_amdgcn_rcpf(den1); i1 = i1 * fmaf(-den1, i1, 2.f);
        vj0 = (fmaf(cmj, vj0, gvl) + n0) * i0;
        vj1 = (fmaf(cmj, vj1, gvl) + n1) * i1;
        vbuf[(u + 1) & 1][j + (j >> 4)] = make_float2(vj0, vj1);
      }
      __syncthreads();                           // the ONLY barrier per unfold
    }
  }

  // ---- MLP head (final v sits in vbuf[0] after 6 flips) ----
  if (tid < 128) {
    int g = tid >> 6, d = tid & 63;
    float acc = fc1_b[d];
    for (int u = 0; u < 128; u++) {
      float2 v2 = vbuf[0][u + (u >> 4)];
      acc = fmaf(g ? v2.y : v2.x, fc1_w[d * 128 + u], acc);
    }
    red[g][d] = fmaxf(acc, 0.f) * fc2_w[d];
  }
  __syncthreads();
  if (tid < 2) {
    float s = fc2_b[0];
    for (int d = 0; d < 64; d++) s += red[tid][d];
    out[b0 + tid] = s;
  }
}

// ------------------------------- launcher ----------------------------------
extern "C" void kernel_launch(void* const* d_in, const int* in_sizes, int n_in,
                              void* d_out, int out_size, void* d_ws, size_t ws_size,
                              hipStream_t stream) {
  (void)in_sizes; (void)n_in; (void)out_size; (void)ws_size;
  char* ws = (char*)d_ws;
  // 32MB envelope, time-multiplexed:
  //   P1 [0,16M) live conv1->conv2; tables [0,448K) after conv2 (prep);
  //   feats [16M,32M) live conv2->lnn.
  float*  P1   = (float*)(ws);
  float*  feats= (float*)(ws + (16 << 20));
  float2* R12T = (float2*)(ws + 0);             // 128KB
  float*  VTT  = (float*)(ws + (128 << 10));    // 64KB
  float4* S4T  = (float4*)(ws + (192 << 10));   // 256KB -> ends 448KB

  conv1_kernel<<<512, 512, 0, stream>>>((const float*)d_in[0],
      (const float*)d_in[1], (const float*)d_in[2], P1);
  conv2_kernel<<<512, 512, 0, stream>>>(P1,
      (const float*)d_in[3], (const float*)d_in[4], feats);
  prep_kernel<<<64, 256, 0, stream>>>(
      (const float*)d_in[7], (const float*)d_in[8],
      (const float*)d_in[9], (const float*)d_in[10],
      (const float*)d_in[11], (const float*)d_in[12],
      (const float*)d_in[13], (const float*)d_in[14],
      (const float*)d_in[5], (const float*)d_in[6],
      R12T, VTT, S4T);
  lnn_kernel<<<256, 1024, 0, stream>>>(R12T, VTT, S4T, feats,
      (const float*)d_in[17], (const float*)d_in[16], (const float*)d_in[15],
      (const float*)d_in[18], (const float*)d_in[19],
      (const float*)d_in[20], (const float*)d_in[21],
      (float*)d_out);
}

// Round 4
// 1277.272 us; speedup vs baseline: 1.5803x; 1.0255x over previous
//
#include <hip/hip_runtime.h>
#include <hip/hip_bf16.h>

// ---------------------------------------------------------------------------
// HybridCnnLnn R19: unlock the 128-VGPR budget, tables -> registers.
// Ledger: R15 1085us (psum serial reduce). R16/R17 spilled: VGPR_Count=64 in
// ALL rounds incl. spilling ones => allocator BUDGET was 64; launch_bounds'
// 2nd arg never raised it. R18 (butterfly, r12 in LDS) 1179us: unfold loop
// re-reads the whole 128KB r12 table per unfold (~165us LDS pipe) + addr adds.
// R19: __attribute__((amdgpu_waves_per_eu(4,4))) pins 4 waves/EU -> 128 VGPR
// cap at unchanged occupancy (4 waves/SIMD was leaving half the RF idle).
//  - r12(32)+vw(16)+sw(16) = 64 regs resident; unfold inner loop = pure
//    register math + 8-addr broadcast vbuf read. LDS 136KB -> ~5KB.
//  - sensory (s1,s2) float2 streamed from L2 per t (t-invariant, L2-hot).
//  - leader split: butterfly sums are bit-identical on all 8 lanes, so
//    h=0/h=1 lanes each update one batch's v (halves serial rcp-NR tail).
// Bit-identical arithmetic -> absmax 0.0 expected.
// Tripwire: VGPR=64 + MB-scale WRITE_SIZE => attr ignored => revert tables.
// ---------------------------------------------------------------------------

#define L2E 1.4426950408889634f

// ---------------- prep: fold params, transpose to [n][j*8+h] ---------------
__global__ __launch_bounds__(256)
void prep_kernel(const float* __restrict__ smu, const float* __restrict__ ssig,
                 const float* __restrict__ sW,  const float* __restrict__ serev,
                 const float* __restrict__ mu,  const float* __restrict__ sig,
                 const float* __restrict__ W,   const float* __restrict__ erev,
                 const float* __restrict__ in_w, const float* __restrict__ in_b,
                 float2* __restrict__ R12T, float* __restrict__ VTT,
                 float2* __restrict__ S2T, float* __restrict__ SWT) {
  int idx = blockIdx.x * 256 + threadIdx.x;      // idx = i*128 + j
  int i = idx >> 7, j = idx & 127;
  int h = i >> 4, n = i & 15;
  int dst = n * 1024 + j * 8 + h;                // lane-major for lnn mapping
  float r1 = sig[idx] * L2E;
  R12T[dst] = make_float2(r1, mu[idx] * r1);     // arg = r2 - r1*v
  VTT[dst]  = W[idx] * erev[idx];                // |erev|=1 -> |VT| = W
  float ss = ssig[idx] * L2E;
  S2T[dst] = make_float2(ss * in_w[i], (smu[idx] - in_b[i]) * ss);
  SWT[dst] = sW[idx] * serev[idx];
}

// ----------------------------- conv1 (k=5, tiled) --------------------------
// x [512,256,24] -> P1 [512,64,128] ([b][co][t']), relu+maxpool2 fused
__launch_bounds__(512)
__global__ void conv1_kernel(const float* __restrict__ x, const float* __restrict__ w1,
                             const float* __restrict__ b1, float* __restrict__ P1) {
  __shared__ float xs[6240];                     // rows t in [-2,258), 24 ch
  int tid = threadIdx.x, b = blockIdx.x;
  const float* xb = x + (size_t)b * 6144;
  for (int idx = tid; idx < 6144; idx += 512) xs[idx + 48] = xb[idx];
  if (tid < 48) { xs[tid] = 0.f; xs[6192 + tid] = 0.f; }
  __syncthreads();
  int tp = tid & 127, cq = tid >> 7;             // 128 pooled t x 4 co-quarters
  float acc0[16], acc1[16];
#pragma unroll
  for (int n = 0; n < 16; n++) { float bb = b1[cq * 16 + n]; acc0[n] = bb; acc1[n] = bb; }
  for (int cic = 0; cic < 3; cic++) {            // ci chunks of 8
    float p[6][8];
#pragma unroll
    for (int r = 0; r < 6; r++) {
      const float* row = &xs[(2 * tp + r) * 24 + cic * 8];
      float4 a = *(const float4*)row;
      float4 c = *(const float4*)(row + 4);
      p[r][0] = a.x; p[r][1] = a.y; p[r][2] = a.z; p[r][3] = a.w;
      p[r][4] = c.x; p[r][5] = c.y; p[r][6] = c.z; p[r][7] = c.w;
    }
#pragma unroll
    for (int n = 0; n < 16; n++) {
      const float* wr = w1 + (cq * 16 + n) * 120 + cic * 40;  // uniform -> s_load
#pragma unroll
      for (int c = 0; c < 8; c++) {
#pragma unroll
        for (int kk = 0; kk < 5; kk++) {
          float w = wr[c * 5 + kk];
          acc0[n] = fmaf(p[kk][c],     w, acc0[n]);
          acc1[n] = fmaf(p[kk + 1][c], w, acc1[n]);
        }
      }
    }
  }
  float* pb = P1 + (size_t)b * 8192;
#pragma unroll
  for (int n = 0; n < 16; n++)
    pb[(cq * 16 + n) * 128 + tp] = fmaxf(fmaxf(acc0[n], acc1[n]), 0.f);
}

// ----------------------------- conv2 (k=3, tiled) --------------------------
// P1 [512,64,128] -> feats [512,64,128] laid out [b][t'][co]
__launch_bounds__(512)
__global__ void conv2_kernel(const float* __restrict__ P1, const float* __restrict__ w2,
                             const float* __restrict__ b2, float* __restrict__ feats) {
  __shared__ float xs[8450];                     // [t+1][ci], stride 65
  int tid = threadIdx.x, b = blockIdx.x;
  const float* pb = P1 + (size_t)b * 8192;
  for (int idx = tid; idx < 8192; idx += 512) {
    int ci = idx >> 7, t = idx & 127;
    xs[(t + 1) * 65 + ci] = pb[idx];
  }
  if (tid < 65) { xs[tid] = 0.f; xs[129 * 65 + tid] = 0.f; }
  __syncthreads();
  int tp = tid & 63, cq = tid >> 6;              // 64 pooled t x 8 co-octants
  float acc0[16], acc1[16];
#pragma unroll
  for (int n = 0; n < 16; n++) { float bb = b2[cq * 16 + n]; acc0[n] = bb; acc1[n] = bb; }
  for (int cic = 0; cic < 8; cic++) {            // ci chunks of 8
    float p[4][8];
#pragma unroll
    for (int r = 0; r < 4; r++)
#pragma unroll
      for (int c = 0; c < 8; c++)
        p[r][c] = xs[(2 * tp + r) * 65 + cic * 8 + c];
#pragma unroll
    for (int n = 0; n < 16; n++) {
      const float* wr = w2 + (cq * 16 + n) * 192 + cic * 24;  // native [co][ci][kk]
#pragma unroll
      for (int c = 0; c < 8; c++) {
#pragma unroll
        for (int kk = 0; kk < 3; kk++) {
          float w = wr[c * 3 + kk];
          acc0[n] = fmaf(p[kk][c],     w, acc0[n]);
          acc1[n] = fmaf(p[kk + 1][c], w, acc1[n]);
        }
      }
    }
  }
  __syncthreads();                               // reuse xs as [tp][co]
#pragma unroll
  for (int n = 0; n < 16; n += 4) {
    float4 v;
    v.x = fmaxf(fmaxf(acc0[n],     acc1[n]),     0.f);
    v.y = fmaxf(fmaxf(acc0[n + 1], acc1[n + 1]), 0.f);
    v.z = fmaxf(fmaxf(acc0[n + 2], acc1[n + 2]), 0.f);
    v.w = fmaxf(fmaxf(acc0[n + 3], acc1[n + 3]), 0.f);
    *(float4*)&xs[tp * 128 + cq * 16 + n] = v;
  }
  __syncthreads();
  float* fb = feats + (size_t)b * 8192;
  for (int idx = tid; idx < 8192; idx += 512) fb[idx] = xs[idx];
}

// --------------------------- LTC recurrence + head -------------------------
// block = 1024: h = tid&7 (i-octant), j = tid>>3 (unit). 2 batches/block,
// grid 256 = 1 block/CU, 4 waves/SIMD pinned via amdgpu_waves_per_eu(4,4)
// -> 128-VGPR budget. r12/vw/sw tables resident in 64 regs; sensory (s1,s2)
// streamed from L2. Per-unfold: 16 pure-reg iters + broadcast vbuf read ->
// 3x shfl_xor butterfly -> h<2 dual-lane leader update -> ONE barrier.
__global__ void __launch_bounds__(1024) __attribute__((amdgpu_waves_per_eu(4, 4)))
lnn_kernel(const float2* __restrict__ R12T, const float* __restrict__ VTT,
           const float2* __restrict__ S2T, const float* __restrict__ SWT,
           const float* __restrict__ feats,
           const float* __restrict__ cm_t, const float* __restrict__ gleak,
           const float* __restrict__ vleak,
           const float* __restrict__ fc1_w, const float* __restrict__ fc1_b,
           const float* __restrict__ fc2_w, const float* __restrict__ fc2_b,
           float* __restrict__ out) {
  __shared__ float2 xt2[2][136];                 // feats double-buffer, padded
  __shared__ float2 vbuf[2][136];                // ping-pong v, padded slots
  __shared__ float red[2][64];
  int tid = threadIdx.x;
  int h = tid & 7, j = tid >> 3;
  int b0 = blockIdx.x * 2;

  // tables -> registers (coalesced [n][tid] layout from prep): 64 VGPRs
  float2 r12[16]; float vw[16], sw[16];
#pragma unroll
  for (int n = 0; n < 16; n++) {
    r12[n] = R12T[n * 1024 + tid];
    vw[n]  = VTT[n * 1024 + tid];
    sw[n]  = SWT[n * 1024 + tid];
  }

  float cmj = cm_t[j], glk = gleak[j];
  float gvl = glk * vleak[j], cgl = cmj + glk;
  float vj0 = 0.f, vj1 = 0.f;
  if (tid < 136) vbuf[0][tid] = make_float2(0.f, 0.f);
  const float* f0 = feats + (size_t)b0 * 8192;
  const float* f1 = f0 + 8192;
  if (tid < 128) xt2[0][tid + (tid >> 4)] = make_float2(f0[tid], f1[tid]);
  __syncthreads();

  const int hb = 17 * h;                         // slot base: 16h + n + h
  const float2* s2p = S2T + tid;

  for (int t = 0; t < 64; t++) {
    // prefetch feats for t+1; LDS-write parked at unfold u=4
    float pf0 = 0.f, pf1 = 0.f;
    if (tid < 128 && t < 63) {
      pf0 = f0[(t + 1) * 128 + tid];
      pf1 = f1[(t + 1) * 128 + tid];
    }

    // ---- sensory partials (s2 streamed from L2; sw resident) ----
    float sn0 = 0.f, sd0 = 0.f, sn1 = 0.f, sd1 = 0.f;
    {
      const float2* xb = xt2[t & 1];
#pragma unroll 8
      for (int n = 0; n < 16; n++) {
        float2 s = s2p[n * 1024];
        float2 xv = xb[hb + n];
        float q0 = __builtin_amdgcn_rcpf(1.f + __builtin_amdgcn_exp2f(fmaf(-s.x, xv.x, s.y)));
        sn0 = fmaf(sw[n], q0, sn0); sd0 = fmaf(fabsf(sw[n]), q0, sd0);
        float q1 = __builtin_amdgcn_rcpf(1.f + __builtin_amdgcn_exp2f(fmaf(-s.x, xv.y, s.y)));
        sn1 = fmaf(sw[n], q1, sn1); sd1 = fmaf(fabsf(sw[n]), q1, sd1);
      }
    }

    // ---- 6 semi-implicit ODE unfolds (pure-register inner loop) ----
    for (int u = 0; u < 6; u++) {
      float n0 = sn0, d0 = sd0, n1 = sn1, d1 = sd1;
      const float2* vb = vbuf[u & 1] + hb;
#pragma unroll
      for (int n = 0; n < 16; n++) {
        float2 rr = r12[n];                      // registers
        float2 v2 = vb[n];                       // 8-addr broadcast, conflict-free
        float q0 = __builtin_amdgcn_rcpf(1.f + __builtin_amdgcn_exp2f(fmaf(-rr.x, v2.x, rr.y)));
        n0 = fmaf(vw[n], q0, n0); d0 = fmaf(fabsf(vw[n]), q0, d0);
        float q1 = __builtin_amdgcn_rcpf(1.f + __builtin_amdgcn_exp2f(fmaf(-rr.x, v2.y, rr.y)));
        n1 = fmaf(vw[n], q1, n1); d1 = fmaf(fabsf(vw[n]), q1, d1);
      }
      // butterfly allreduce over the 8 octant lanes (bit-identical per lane)
#pragma unroll
      for (int m = 1; m < 8; m <<= 1) {
        n0 += __shfl_xor(n0, m, 64);
        d0 += __shfl_xor(d0, m, 64);
        n1 += __shfl_xor(n1, m, 64);
        d1 += __shfl_xor(d1, m, 64);
      }
      if (u == 4 && tid < 128 && t < 63)         // park prefetched feats
        xt2[(t + 1) & 1][tid + (tid >> 4)] = make_float2(pf0, pf1);
      if (h < 2) {                               // dual-lane leader: batch = h
        float nn = h ? n1 : n0, dd = h ? d1 : d0;
        float vj = h ? vj1 : vj0;
        float den = cgl + dd;
        float ii = __builtin_amdgcn_rcpf(den); ii = ii * fmaf(-den, ii, 2.f);
        vj = (fmaf(cmj, vj, gvl) + nn) * ii;
        if (h) vj1 = vj; else vj0 = vj;
        ((float*)vbuf[(u + 1) & 1])[(j + (j >> 4)) * 2 + h] = vj;
      }
      __syncthreads();                           // the ONLY barrier per unfold
    }
  }

  // ---- MLP head (final v sits in vbuf[0] after 6 flips) ----
  if (tid < 128) {
    int g = tid >> 6, d = tid & 63;
    float acc = fc1_b[d];
    for (int u = 0; u < 128; u++) {
      float2 v2 = vbuf[0][u + (u >> 4)];
      acc = fmaf(g ? v2.y : v2.x, fc1_w[d * 128 + u], acc);
    }
    red[g][d] = fmaxf(acc, 0.f) * fc2_w[d];
  }
  __syncthreads();
  if (tid < 2) {
    float s = fc2_b[0];
    for (int d = 0; d < 64; d++) s += red[tid][d];
    out[b0 + tid] = s;
  }
}

// ------------------------------- launcher ----------------------------------
extern "C" void kernel_launch(void* const* d_in, const int* in_sizes, int n_in,
                              void* d_out, int out_size, void* d_ws, size_t ws_size,
                              hipStream_t stream) {
  (void)in_sizes; (void)n_in; (void)out_size; (void)ws_size;
  char* ws = (char*)d_ws;
  // 32MB envelope, time-multiplexed:
  //   P1 [0,16M) live conv1->conv2; tables [0,384K) after conv2 (prep);
  //   feats [16M,32M) live conv2->lnn.
  float*  P1   = (float*)(ws);
  float*  feats= (float*)(ws + (16 << 20));
  float2* R12T = (float2*)(ws + 0);             // 128KB
  float*  VTT  = (float*)(ws + (128 << 10));    // 64KB
  float2* S2T  = (float2*)(ws + (192 << 10));   // 128KB
  float*  SWT  = (float*)(ws + (320 << 10));    // 64KB -> ends 384KB

  conv1_kernel<<<512, 512, 0, stream>>>((const float*)d_in[0],
      (const float*)d_in[1], (const float*)d_in[2], P1);
  conv2_kernel<<<512, 512, 0, stream>>>(P1,
      (const float*)d_in[3], (const float*)d_in[4], feats);
  prep_kernel<<<64, 256, 0, stream>>>(
      (const float*)d_in[7], (const float*)d_in[8],
      (const float*)d_in[9], (const float*)d_in[10],
      (const float*)d_in[11], (const float*)d_in[12],
      (const float*)d_in[13], (const float*)d_in[14],
      (const float*)d_in[5], (const float*)d_in[6],
      R12T, VTT, S2T, SWT);
  lnn_kernel<<<256, 1024, 0, stream>>>(R12T, VTT, S2T, SWT, feats,
      (const float*)d_in[17], (const float*)d_in[16], (const float*)d_in[15],
      (const float*)d_in[18], (const float*)d_in[19],
      (const float*)d_in[20], (const float*)d_in[21],
      (float*)d_out);
}